// Round 5
// baseline (105.346 us; speedup 1.0000x reference)
//
#include <hip/hip_runtime.h>
#include <math.h>

// rbfLayer: N=100k points, DEG=16 neighbors, NB=MB=4 bases, FIN=FOUT=8.
// out[u,i] = sum_{e in u} sum_{n,m,j} c_e[n] f_e[m] K[i,j,n,m] feat[nbr_e, j]
// Per-point moment tensor G[n,m,j] over edges, then one K-contraction/point.
// 4 threads/point: (j-half) x (edge-half). Pair lanes (2k,2k+1) share trig:
// each computes basis for alternating edges, exchanged via shfl_xor(.,1).

#define TWO_OVER_PI 0.63661977236758134f

__device__ __forceinline__ float fast_atan2f(float y, float x) {
    float ax = fabsf(x), ay = fabsf(y);
    float mx = fmaxf(ax, ay);
    float mn = fminf(ax, ay);
    mx = fmaxf(mx, 1e-30f);                      // guard rcp(0)
    float r = mn * __builtin_amdgcn_rcpf(mx);
    float s = r * r;
    float p = -0.0117212f;                       // minimax atan on [0,1]
    p = fmaf(p, s,  0.05265332f);
    p = fmaf(p, s, -0.11643287f);
    p = fmaf(p, s,  0.19354346f);
    p = fmaf(p, s, -0.33262347f);
    p = fmaf(p, s,  0.99997726f);
    float a = p * r;
    a = (ay > ax) ? (1.57079632679f - a) : a;    // fold octant
    a = (x < 0.0f) ? (3.14159265359f - a) : a;   // fold quadrant
    return copysignf(a, y);
}

__device__ __forceinline__ void edge_basis(float dx, float dy,
                                           float c[4], float f[4]) {
    float dist = sqrtf(fmaf(dx, dx, dy * dy));
    float tr = dist * 1.5f;                       // radial hat coordinate
    float theta = fast_atan2f(dy, dx);
    float ta = fmaf(theta, TWO_OVER_PI, 2.0f);    // angular in [0,4]
#pragma unroll
    for (int n = 0; n < 4; ++n)
        c[n] = fmaxf(1.0f - fabsf(tr - (float)n), 0.0f);
#pragma unroll
    for (int m = 0; m < 4; ++m) {
        float d = fabsf(ta - (float)m);
        d = fminf(d, 4.0f - d);                   // periodic wrap (period 4)
        f[m] = fmaxf(1.0f - d, 0.0f);
    }
}

__global__ __launch_bounds__(256) void rbf_kernel(
    const float* __restrict__ positions,
    const float* __restrict__ features,
    const float* __restrict__ kern,
    const int*   __restrict__ neighbors,
    const int*   __restrict__ row_splits,
    float*       __restrict__ out,
    int npts)
{
    __shared__ float Kl[1024];   // K[i][j][n][m], i*128 + j*16 + n*4 + m
    {
        const float4* src = (const float4*)kern;
        float4* dst = (float4*)Kl;
        dst[threadIdx.x] = src[threadIdx.x];
    }
    __syncthreads();

    int gt   = blockIdx.x * blockDim.x + threadIdx.x;
    int u    = gt >> 2;
    int sub  = gt & 3;
    int half = sub & 1;      // j-half: feature/K columns [half*4, half*4+4)
    int eh   = sub >> 1;     // edge-half: edges [rs0+eh*8, rs0+eh*8+8)
    if (u >= npts) return;

    float2 pu = ((const float2*)positions)[u];
    int rs0 = row_splits[u];
    int rs1 = row_splits[u + 1];
    int cnt = rs1 - rs0;

    float g[16][4];
#pragma unroll
    for (int nm = 0; nm < 16; ++nm)
#pragma unroll
        for (int j = 0; j < 4; ++j) g[nm][j] = 0.0f;

    const float2* pos2  = (const float2*)positions;
    const float4* feat4 = (const float4*)features;

    if (cnt == 16) {
        int e0 = rs0 + eh * 8;
        const int4* nb4 = (const int4*)(neighbors + e0);
        int4 nA = nb4[0];
        int4 nB = nb4[1];

        // Pair p handles local edges (2p, 2p+1). "Own" edge parity == half.
        int nbO0 = half ? nA.y : nA.x,  nbP0 = half ? nA.x : nA.y;
        int nbO1 = half ? nA.w : nA.z,  nbP1 = half ? nA.z : nA.w;
        int nbO2 = half ? nB.y : nB.x,  nbP2 = half ? nB.x : nB.y;
        int nbO3 = half ? nB.w : nB.z,  nbP3 = half ? nB.z : nB.w;

        // Issue all 12 gathers up front (4 pos + 8 feat) for deep MLP.
        float2 pO0 = pos2[nbO0];
        float2 pO1 = pos2[nbO1];
        float2 pO2 = pos2[nbO2];
        float2 pO3 = pos2[nbO3];
        float4 vO0 = feat4[nbO0 * 2 + half];
        float4 vP0 = feat4[nbP0 * 2 + half];
        float4 vO1 = feat4[nbO1 * 2 + half];
        float4 vP1 = feat4[nbP1 * 2 + half];
        float4 vO2 = feat4[nbO2 * 2 + half];
        float4 vP2 = feat4[nbP2 * 2 + half];
        float4 vO3 = feat4[nbO3 * 2 + half];
        float4 vP3 = feat4[nbP3 * 2 + half];

#define DO_PAIR(pO, vO, vP)                                                   \
        {                                                                     \
            float cO[4], fO[4], cP[4], fP[4];                                 \
            edge_basis(pO.x - pu.x, pO.y - pu.y, cO, fO);                     \
            _Pragma("unroll")                                                 \
            for (int k = 0; k < 4; ++k) {                                     \
                cP[k] = __shfl_xor(cO[k], 1);                                 \
                fP[k] = __shfl_xor(fO[k], 1);                                 \
            }                                                                 \
            float aO[4] = {vO.x, vO.y, vO.z, vO.w};                           \
            float aP[4] = {vP.x, vP.y, vP.z, vP.w};                           \
            _Pragma("unroll")                                                 \
            for (int n = 0; n < 4; ++n)                                       \
                _Pragma("unroll")                                             \
                for (int m = 0; m < 4; ++m) {                                 \
                    float wO = cO[n] * fO[m];                                 \
                    float wP = cP[n] * fP[m];                                 \
                    _Pragma("unroll")                                         \
                    for (int j = 0; j < 4; ++j) {                             \
                        g[n * 4 + m][j] = fmaf(wO, aO[j], g[n * 4 + m][j]);   \
                        g[n * 4 + m][j] = fmaf(wP, aP[j], g[n * 4 + m][j]);   \
                    }                                                         \
                }                                                             \
        }

        DO_PAIR(pO0, vO0, vP0)
        DO_PAIR(pO1, vO1, vP1)
        DO_PAIR(pO2, vO2, vP2)
        DO_PAIR(pO3, vO3, vP3)
#undef DO_PAIR
    } else {
        // Generic path (not exercised for uniform DEG=16, kept for safety).
        int c0 = (cnt + 1) >> 1;
        int e0 = rs0 + eh * c0;
        int e1 = (eh == 0) ? (rs0 + c0) : rs1;
        for (int e = e0; e < e1; ++e) {
            int nb = neighbors[e];
            float2 pn = pos2[nb];
            float c[4], f[4];
            edge_basis(pn.x - pu.x, pn.y - pu.y, c, f);
            float4 fv = feat4[nb * 2 + half];
            float fvj[4] = {fv.x, fv.y, fv.z, fv.w};
#pragma unroll
            for (int n = 0; n < 4; ++n)
#pragma unroll
                for (int m = 0; m < 4; ++m) {
                    float w = c[n] * f[m];
#pragma unroll
                    for (int j = 0; j < 4; ++j)
                        g[n * 4 + m][j] = fmaf(w, fvj[j], g[n * 4 + m][j]);
                }
        }
    }

    // Final contraction: o[i] = sum_{j in half, nm} K[i, jg, nm] * g[nm][j]
    float o[8];
#pragma unroll
    for (int i = 0; i < 8; ++i) o[i] = 0.0f;

    const float4* K4 = (const float4*)Kl;
#pragma unroll
    for (int i = 0; i < 8; ++i) {
#pragma unroll
        for (int j = 0; j < 4; ++j) {
            int jg = half * 4 + j;
            int base4 = (i * 128 + jg * 16) >> 2;
#pragma unroll
            for (int q = 0; q < 4; ++q) {
                float4 kv = K4[base4 + q];
                o[i] = fmaf(kv.x, g[q * 4 + 0][j], o[i]);
                o[i] = fmaf(kv.y, g[q * 4 + 1][j], o[i]);
                o[i] = fmaf(kv.z, g[q * 4 + 2][j], o[i]);
                o[i] = fmaf(kv.w, g[q * 4 + 3][j], o[i]);
            }
        }
    }

    // Reduce over the 4 lanes of this point.
#pragma unroll
    for (int i = 0; i < 8; ++i) {
        o[i] += __shfl_xor(o[i], 1);
        o[i] += __shfl_xor(o[i], 2);
    }

    float2 ov = (sub == 0) ? make_float2(o[0], o[1])
              : (sub == 1) ? make_float2(o[2], o[3])
              : (sub == 2) ? make_float2(o[4], o[5])
                           : make_float2(o[6], o[7]);
    ((float2*)out)[u * 4 + sub] = ov;
}

extern "C" void kernel_launch(void* const* d_in, const int* in_sizes, int n_in,
                              void* d_out, int out_size, void* d_ws, size_t ws_size,
                              hipStream_t stream) {
    const float* positions  = (const float*)d_in[0];
    const float* features   = (const float*)d_in[1];
    const float* kern       = (const float*)d_in[2];
    const int*   neighbors  = (const int*)d_in[3];
    const int*   row_splits = (const int*)d_in[4];
    float* out = (float*)d_out;

    int npts = in_sizes[0] / 2;
    int total = npts * 4;
    int block = 256;
    int grid = (total + block - 1) / block;
    rbf_kernel<<<grid, block, 0, stream>>>(positions, features, kern,
                                           neighbors, row_splits, out, npts);
}

// Round 7
// 102.337 us; speedup vs baseline: 1.0294x; 1.0294x over previous
//
#include <hip/hip_runtime.h>
#include <hip/hip_fp16.h>
#include <math.h>

// rbfLayer: N=100k points, DEG=16 neighbors, NB=MB=4 bases, FIN=FOUT=8.
// out[u,i] = sum_{e,n,m,j} c_e[n] f_e[m] K[i,j,n,m] feat[nbr_e, j]
// Per-point moment tensor G[n,m,j], then one K-contraction per point.
// 4 threads/point: (j-half) x (edge-half), 8 edges/thread, no shuffles.
// Pre-pass packs [px f32, py f32, f0..f7 f16] into one 32B record so each
// edge gather touches exactly ONE 64B line (was 2: pos line + feat line).

#define TWO_OVER_PI 0.63661977236758134f

__device__ __forceinline__ float fast_atan2f(float y, float x) {
    float ax = fabsf(x), ay = fabsf(y);
    float mx = fmaxf(ax, ay);
    float mn = fminf(ax, ay);
    mx = fmaxf(mx, 1e-30f);                      // guard rcp(0)
    float r = mn * __builtin_amdgcn_rcpf(mx);
    float s = r * r;
    float p = -0.0117212f;                       // minimax atan on [0,1]
    p = fmaf(p, s,  0.05265332f);
    p = fmaf(p, s, -0.11643287f);
    p = fmaf(p, s,  0.19354346f);
    p = fmaf(p, s, -0.33262347f);
    p = fmaf(p, s,  0.99997726f);
    float a = p * r;
    a = (ay > ax) ? (1.57079632679f - a) : a;    // fold octant
    a = (x < 0.0f) ? (3.14159265359f - a) : a;   // fold quadrant
    return copysignf(a, y);
}

__device__ __forceinline__ void edge_basis(float dx, float dy,
                                           float c[4], float f[4]) {
    float dist = sqrtf(fmaf(dx, dx, dy * dy));
    float tr = dist * 1.5f;                       // radial hat coordinate
    float theta = fast_atan2f(dy, dx);
    float ta = fmaf(theta, TWO_OVER_PI, 2.0f);    // angular in [0,4]
#pragma unroll
    for (int n = 0; n < 4; ++n)
        c[n] = fmaxf(1.0f - fabsf(tr - (float)n), 0.0f);
#pragma unroll
    for (int m = 0; m < 4; ++m) {
        float d = fabsf(ta - (float)m);
        d = fminf(d, 4.0f - d);                   // periodic wrap (period 4)
        f[m] = fmaxf(1.0f - d, 0.0f);
    }
}

__device__ __forceinline__ float2 h2f(float bits) {
    union { float f; __half2 h; } u;
    u.f = bits;
    return make_float2(__low2float(u.h), __high2float(u.h));
}

__device__ __forceinline__ float h2f_pack(float a, float b) {
    union { __half2 h; float f; } u;
    u.h = __floats2half2_rn(a, b);
    return u.f;
}

// ---- Pre-pass: packed[u] = { px, py, h(f0,f1), h(f2,f3) | h(f4,f5), h(f6,f7), 0, 0 }
__global__ __launch_bounds__(256) void pack_kernel(
    const float* __restrict__ positions,
    const float* __restrict__ features,
    float4*      __restrict__ packed,    // 2 float4 per point (32B record)
    int npts)
{
    int u = blockIdx.x * blockDim.x + threadIdx.x;
    if (u >= npts) return;
    float2 p  = ((const float2*)positions)[u];
    float4 fa = ((const float4*)features)[u * 2];
    float4 fb = ((const float4*)features)[u * 2 + 1];
    float4 q0, q1;
    q0.x = p.x;
    q0.y = p.y;
    q0.z = h2f_pack(fa.x, fa.y);
    q0.w = h2f_pack(fa.z, fa.w);
    q1.x = h2f_pack(fb.x, fb.y);
    q1.y = h2f_pack(fb.z, fb.w);
    q1.z = 0.0f;
    q1.w = 0.0f;
    packed[u * 2]     = q0;
    packed[u * 2 + 1] = q1;
}

// ---- Main kernel (packed path)
__global__ __launch_bounds__(256) void rbf_packed_kernel(
    const float* __restrict__ positions,
    const float4* __restrict__ packed,
    const float* __restrict__ kern,
    const int*   __restrict__ neighbors,
    const int*   __restrict__ row_splits,
    float*       __restrict__ out,
    int npts)
{
    __shared__ float Kl[1024];   // K[i][j][n][m], i*128 + j*16 + n*4 + m
    {
        const float4* src = (const float4*)kern;
        float4* dst = (float4*)Kl;
        dst[threadIdx.x] = src[threadIdx.x];
    }
    __syncthreads();

    int gt   = blockIdx.x * blockDim.x + threadIdx.x;
    int u    = gt >> 2;
    int sub  = gt & 3;
    int half = sub & 1;      // j-half: feature/K columns [half*4, half*4+4)
    int eh   = sub >> 1;     // edge-half: edges [rs0+eh*8, rs0+eh*8+8)
    if (u >= npts) return;

    float2 pu = ((const float2*)positions)[u];
    int rs0 = row_splits[u];
    int rs1 = row_splits[u + 1];
    int cnt = rs1 - rs0;

    float g[16][4];
#pragma unroll
    for (int nm = 0; nm < 16; ++nm)
#pragma unroll
        for (int j = 0; j < 4; ++j) g[nm][j] = 0.0f;

#define VISIT(A, C)                                                           \
    {                                                                         \
        float c[4], f[4];                                                     \
        edge_basis(A.x - pu.x, A.y - pu.y, c, f);                             \
        float2 lo = h2f(half ? C.x : A.z);                                    \
        float2 hi = h2f(half ? C.y : A.w);                                    \
        float fvj[4] = {lo.x, lo.y, hi.x, hi.y};                              \
        _Pragma("unroll")                                                     \
        for (int n = 0; n < 4; ++n)                                           \
            _Pragma("unroll")                                                 \
            for (int m = 0; m < 4; ++m) {                                     \
                float w = c[n] * f[m];                                        \
                _Pragma("unroll")                                             \
                for (int j = 0; j < 4; ++j)                                   \
                    g[n * 4 + m][j] = fmaf(w, fvj[j], g[n * 4 + m][j]);       \
            }                                                                 \
    }

    if (cnt == 16) {
        int e0 = rs0 + eh * 8;
        const int4* nb4 = (const int4*)(neighbors + e0);
        int4 nA = nb4[0];
        int4 nB = nb4[1];
#pragma unroll
        for (int grp = 0; grp < 2; ++grp) {
            int nb0 = grp ? nB.x : nA.x;
            int nb1 = grp ? nB.y : nA.y;
            int nb2 = grp ? nB.z : nA.z;
            int nb3 = grp ? nB.w : nA.w;
            // 8 loads to 4 lines issued up-front; pair lanes hit same lines.
            float4 A0 = packed[nb0 * 2], C0 = packed[nb0 * 2 + 1];
            float4 A1 = packed[nb1 * 2], C1 = packed[nb1 * 2 + 1];
            float4 A2 = packed[nb2 * 2], C2 = packed[nb2 * 2 + 1];
            float4 A3 = packed[nb3 * 2], C3 = packed[nb3 * 2 + 1];
            VISIT(A0, C0)
            VISIT(A1, C1)
            VISIT(A2, C2)
            VISIT(A3, C3)
        }
    } else {
        // Generic path (uniform DEG=16 never takes this; kept for safety).
        int c0 = (cnt + 1) >> 1;
        int e0 = rs0 + eh * c0;
        int e1 = (eh == 0) ? (rs0 + c0) : rs1;
        for (int e = e0; e < e1; ++e) {
            int nb = neighbors[e];
            float4 A = packed[nb * 2];
            float4 C = packed[nb * 2 + 1];
            VISIT(A, C)
        }
    }
#undef VISIT

    // Final contraction: o[i] = sum_{j in half, nm} K[i, jg, nm] * g[nm][j]
    float o[8];
#pragma unroll
    for (int i = 0; i < 8; ++i) o[i] = 0.0f;

    const float4* K4 = (const float4*)Kl;
#pragma unroll
    for (int i = 0; i < 8; ++i) {
#pragma unroll
        for (int j = 0; j < 4; ++j) {
            int jg = half * 4 + j;
            int base4 = (i * 128 + jg * 16) >> 2;
#pragma unroll
            for (int q = 0; q < 4; ++q) {
                float4 kv = K4[base4 + q];
                o[i] = fmaf(kv.x, g[q * 4 + 0][j], o[i]);
                o[i] = fmaf(kv.y, g[q * 4 + 1][j], o[i]);
                o[i] = fmaf(kv.z, g[q * 4 + 2][j], o[i]);
                o[i] = fmaf(kv.w, g[q * 4 + 3][j], o[i]);
            }
        }
    }

#pragma unroll
    for (int i = 0; i < 8; ++i) {
        o[i] += __shfl_xor(o[i], 1);
        o[i] += __shfl_xor(o[i], 2);
    }

    float2 ov = (sub == 0) ? make_float2(o[0], o[1])
              : (sub == 1) ? make_float2(o[2], o[3])
              : (sub == 2) ? make_float2(o[4], o[5])
                           : make_float2(o[6], o[7]);
    ((float2*)out)[u * 4 + sub] = ov;
}

// ---- Fallback (no workspace): R2-style direct gathers, full fp32.
__global__ __launch_bounds__(256) void rbf_direct_kernel(
    const float* __restrict__ positions,
    const float* __restrict__ features,
    const float* __restrict__ kern,
    const int*   __restrict__ neighbors,
    const int*   __restrict__ row_splits,
    float*       __restrict__ out,
    int npts)
{
    __shared__ float Kl[1024];
    {
        const float4* src = (const float4*)kern;
        float4* dst = (float4*)Kl;
        dst[threadIdx.x] = src[threadIdx.x];
    }
    __syncthreads();

    int gt   = blockIdx.x * blockDim.x + threadIdx.x;
    int u    = gt >> 2;
    int sub  = gt & 3;
    int half = sub & 1;
    int eh   = sub >> 1;
    if (u >= npts) return;

    float2 pu = ((const float2*)positions)[u];
    int rs0 = row_splits[u];
    int rs1 = row_splits[u + 1];
    int cnt = rs1 - rs0;

    float g[16][4];
#pragma unroll
    for (int nm = 0; nm < 16; ++nm)
#pragma unroll
        for (int j = 0; j < 4; ++j) g[nm][j] = 0.0f;

    const float2* pos2  = (const float2*)positions;
    const float4* feat4 = (const float4*)features;

    int c0 = (cnt + 1) >> 1;
    int e0 = rs0 + eh * c0;
    int e1 = (eh == 0) ? (rs0 + c0) : rs1;
    for (int e = e0; e < e1; ++e) {
        int nb = neighbors[e];
        float2 pn = pos2[nb];
        float c[4], f[4];
        edge_basis(pn.x - pu.x, pn.y - pu.y, c, f);
        float4 fv = feat4[nb * 2 + half];
        float fvj[4] = {fv.x, fv.y, fv.z, fv.w};
#pragma unroll
        for (int n = 0; n < 4; ++n)
#pragma unroll
            for (int m = 0; m < 4; ++m) {
                float w = c[n] * f[m];
#pragma unroll
                for (int j = 0; j < 4; ++j)
                    g[n * 4 + m][j] = fmaf(w, fvj[j], g[n * 4 + m][j]);
            }
    }

    float o[8];
#pragma unroll
    for (int i = 0; i < 8; ++i) o[i] = 0.0f;
    const float4* K4 = (const float4*)Kl;
#pragma unroll
    for (int i = 0; i < 8; ++i) {
#pragma unroll
        for (int j = 0; j < 4; ++j) {
            int jg = half * 4 + j;
            int base4 = (i * 128 + jg * 16) >> 2;
#pragma unroll
            for (int q = 0; q < 4; ++q) {
                float4 kv = K4[base4 + q];
                o[i] = fmaf(kv.x, g[q * 4 + 0][j], o[i]);
                o[i] = fmaf(kv.y, g[q * 4 + 1][j], o[i]);
                o[i] = fmaf(kv.z, g[q * 4 + 2][j], o[i]);
                o[i] = fmaf(kv.w, g[q * 4 + 3][j], o[i]);
            }
        }
    }
#pragma unroll
    for (int i = 0; i < 8; ++i) {
        o[i] += __shfl_xor(o[i], 1);
        o[i] += __shfl_xor(o[i], 2);
    }
    float2 ov = (sub == 0) ? make_float2(o[0], o[1])
              : (sub == 1) ? make_float2(o[2], o[3])
              : (sub == 2) ? make_float2(o[4], o[5])
                           : make_float2(o[6], o[7]);
    ((float2*)out)[u * 4 + sub] = ov;
}

extern "C" void kernel_launch(void* const* d_in, const int* in_sizes, int n_in,
                              void* d_out, int out_size, void* d_ws, size_t ws_size,
                              hipStream_t stream) {
    const float* positions  = (const float*)d_in[0];
    const float* features   = (const float*)d_in[1];
    const float* kern       = (const float*)d_in[2];
    const int*   neighbors  = (const int*)d_in[3];
    const int*   row_splits = (const int*)d_in[4];
    float* out = (float*)d_out;

    int npts = in_sizes[0] / 2;
    int total = npts * 4;
    int block = 256;
    int grid = (total + block - 1) / block;

    size_t need = (size_t)npts * 32;   // 32B packed record per point
    if (ws_size >= need) {
        int pgrid = (npts + block - 1) / block;
        pack_kernel<<<pgrid, block, 0, stream>>>(positions, features,
                                                 (float4*)d_ws, npts);
        rbf_packed_kernel<<<grid, block, 0, stream>>>(positions,
                                                      (const float4*)d_ws, kern,
                                                      neighbors, row_splits,
                                                      out, npts);
    } else {
        rbf_direct_kernel<<<grid, block, 0, stream>>>(positions, features, kern,
                                                      neighbors, row_splits,
                                                      out, npts);
    }
}